// Round 5
// baseline (32.064 us; speedup 1.0000x reference)
//
#include <hip/hip_runtime.h>

typedef float f32x4 __attribute__((ext_vector_type(4)));

// Abramowitz-Stegun 4.4.45: acos(x) ~ sqrt(1-x)*(a0 + a1 x + a2 x^2 + a3 x^3),
// |err| <= 6.8e-5 on [0,1]. Branchless extension to [-1,1].
__device__ __forceinline__ float poly_p(float a) {
    return fmaf(a, fmaf(a, fmaf(a, -0.0187293f, 0.0742610f), -0.2121144f),
                1.5707288f);
}

__device__ __forceinline__ float fast_acos(float x) {
    float a = fabsf(x);
    float r = sqrtf(fmaxf(1.0f - a, 0.0f)) * poly_p(a);
    return x >= 0.0f ? r : 3.14159265f - r;   // v_cndmask
}

__device__ __forceinline__ float fast_asin(float x) {
    float a = fabsf(x);
    float r = 1.5707963f - sqrtf(fmaxf(1.0f - a, 0.0f)) * poly_p(a);
    return copysignf(r, x);
}

__device__ __forceinline__ void ik_solve(float x, float y,
                                         float c0, float c1,
                                         float l1s, float l2s,
                                         float sumsq, float rden,
                                         float& t1, float& t2) {
    float xs = x * c0;
    float ys = y * c1;
    float dis = fmaf(xs, xs, fmaf(ys, ys, 1e-6f));
    float arg = (dis - sumsq) * rden;
    arg = fminf(fmaxf(arg, -1.0f), 1.0f);
    t2 = fast_acos(arg);
    // cos(t2) == arg, sin(t2) == sqrt(1 - arg^2)  (t2 in [0, pi] so sin >= 0)
    float st2 = sqrtf(fmaxf(fmaf(-arg, arg, 1.0f), 0.0f));
    float num = ys * fmaf(l2s, arg, l1s) - xs * l2s * st2;
    float a1 = num * __builtin_amdgcn_rcpf(dis);   // dis >= 1e-6, approx rcp ok
    a1 = fminf(fmaxf(a1, -1.0f), 1.0f);
    t1 = fast_asin(a1);
}

// Tiny kernel: compute per-mult constants on device (w is device memory;
// can't be read on host under graph capture).
__global__ void Forward_Model_27616639714074_prep(const float* __restrict__ w,
                                                  float* __restrict__ cbuf,
                                                  int n_mults) {
    int ii = threadIdx.x;
    if (ii >= n_mults) return;
    float c0  = fmaxf(rintf(w[ii * 4 + 0]), 0.001f);
    float c1  = fmaxf(rintf(w[ii * 4 + 1]), 0.001f);
    float l1s = 0.5f * fmaxf(rintf(w[ii * 4 + 2]), 0.001f);
    float l2s = 0.5f * fmaxf(rintf(w[ii * 4 + 3]), 0.001f);
    cbuf[ii * 6 + 0] = c0;
    cbuf[ii * 6 + 1] = c1;
    cbuf[ii * 6 + 2] = l1s;
    cbuf[ii * 6 + 3] = l2s;
    cbuf[ii * 6 + 4] = l1s * l1s + l2s * l2s;
    cbuf[ii * 6 + 5] = 1.0f / (2.0f * l1s * l2s + 1e-6f);
}

// One float4 (= two (x,y) pairs) per thread, exact-cover grid, 32-bit
// indexing, non-temporal load/store (streaming data, zero reuse).
__global__ __launch_bounds__(256)
void Forward_Model_27616639714074_kernel_c(const f32x4* __restrict__ in4,
                                           f32x4* __restrict__ out4,
                                           const float* __restrict__ cbuf,
                                           unsigned int n4) {
    float c0 = cbuf[0], c1 = cbuf[1], l1s = cbuf[2], l2s = cbuf[3];
    float sumsq = cbuf[4], rden = cbuf[5];
    unsigned int i = blockIdx.x * 256u + threadIdx.x;
    if (i >= n4) return;
    f32x4 v = __builtin_nontemporal_load(&in4[i]);
    f32x4 r;
    float r0, r1, r2, r3;
    ik_solve(v.x, v.y, c0, c1, l1s, l2s, sumsq, rden, r0, r1);
    ik_solve(v.z, v.w, c0, c1, l1s, l2s, sumsq, rden, r2, r3);
    r.x = r0; r.y = r1; r.z = r2; r.w = r3;
    __builtin_nontemporal_store(r, &out4[i]);
}

// tail: leftover (x,y) pairs past the float4 region (n always even)
__global__ __launch_bounds__(64)
void Forward_Model_27616639714074_tail_c(const float* __restrict__ in,
                                         float* __restrict__ out,
                                         const float* __restrict__ cbuf,
                                         long long pair_start, long long n_pairs) {
    float c0 = cbuf[0], c1 = cbuf[1], l1s = cbuf[2], l2s = cbuf[3];
    float sumsq = cbuf[4], rden = cbuf[5];
    long long p = pair_start + blockIdx.x * 64 + threadIdx.x;
    if (p >= n_pairs) return;
    float t1, t2;
    ik_solve(in[p * 2 + 0], in[p * 2 + 1], c0, c1, l1s, l2s, sumsq, rden, t1, t2);
    out[p * 2 + 0] = t1;
    out[p * 2 + 1] = t2;
}

extern "C" void kernel_launch(void* const* d_in, const int* in_sizes, int n_in,
                              void* d_out, int out_size, void* d_ws, size_t ws_size,
                              hipStream_t stream) {
    const float* in = (const float*)d_in[0];
    const float* w  = (const float*)d_in[1];
    float* out = (float*)d_out;
    float* cbuf = (float*)d_ws;

    long long n = in_sizes[0];           // SIZE*2 floats per mult
    int n_mults = in_sizes[1] / 4;       // N_MULTS

    Forward_Model_27616639714074_prep<<<1, 64, 0, stream>>>(w, cbuf, n_mults);

    unsigned int n4 = (unsigned int)(n >> 2);          // float4 groups
    unsigned int grid = (n4 + 255u) / 256u;
    long long pair_start = ((long long)n4 << 2) >> 1;  // first pair past float4 region
    long long n_pairs = n >> 1;
    long long tail_pairs = n_pairs - pair_start;

    for (int ii = 0; ii < n_mults; ++ii) {
        const f32x4* in4 = reinterpret_cast<const f32x4*>(in);
        f32x4* out4 = reinterpret_cast<f32x4*>(out + (long long)ii * n);
        Forward_Model_27616639714074_kernel_c<<<grid, 256, 0, stream>>>(
            in4, out4, cbuf + ii * 6, n4);
        if (tail_pairs > 0) {
            unsigned int tgrid = (unsigned int)((tail_pairs + 63) / 64);
            Forward_Model_27616639714074_tail_c<<<tgrid, 64, 0, stream>>>(
                in, out + (long long)ii * n, cbuf + ii * 6, pair_start, n_pairs);
        }
    }
}

// Round 6
// 25.445 us; speedup vs baseline: 1.2601x; 1.2601x over previous
//
#include <hip/hip_runtime.h>

typedef float f32x4 __attribute__((ext_vector_type(4)));

// Abramowitz-Stegun 4.4.45: acos(x) ~ sqrt(1-x)*(a0 + a1 x + a2 x^2 + a3 x^3),
// |err| <= 6.8e-5 on [0,1]. Branchless extension to [-1,1].
__device__ __forceinline__ float poly_p(float a) {
    return fmaf(a, fmaf(a, fmaf(a, -0.0187293f, 0.0742610f), -0.2121144f),
                1.5707288f);
}

__device__ __forceinline__ float fast_acos(float x) {
    float a = fabsf(x);
    float r = sqrtf(fmaxf(1.0f - a, 0.0f)) * poly_p(a);
    return x >= 0.0f ? r : 3.14159265f - r;   // v_cndmask
}

__device__ __forceinline__ float fast_asin(float x) {
    float a = fabsf(x);
    float r = 1.5707963f - sqrtf(fmaxf(1.0f - a, 0.0f)) * poly_p(a);
    return copysignf(r, x);
}

__device__ __forceinline__ void ik_solve(float x, float y,
                                         float c0, float c1,
                                         float l1s, float l2s,
                                         float sumsq, float rden,
                                         float& t1, float& t2) {
    float xs = x * c0;
    float ys = y * c1;
    float dis = fmaf(xs, xs, fmaf(ys, ys, 1e-6f));
    float arg = (dis - sumsq) * rden;
    arg = fminf(fmaxf(arg, -1.0f), 1.0f);
    t2 = fast_acos(arg);
    // cos(t2) == arg, sin(t2) == sqrt(1 - arg^2)  (t2 in [0, pi] so sin >= 0)
    float st2 = sqrtf(fmaxf(fmaf(-arg, arg, 1.0f), 0.0f));
    float num = ys * fmaf(l2s, arg, l1s) - xs * l2s * st2;
    float a1 = num * __builtin_amdgcn_rcpf(dis);   // dis >= 1e-6, approx rcp ok
    a1 = fminf(fmaxf(a1, -1.0f), 1.0f);
    t1 = fast_asin(a1);
}

// Single kernel, exact-cover grid: one float4 (= two (x,y) pairs) per thread,
// 32-bit indexing, constants computed per-thread from w (4 broadcast loads,
// L2-cached). Cached loads, NON-TEMPORAL stores (write stream has zero reuse;
// avoid L2 write-allocate thrashing the read stream).
__global__ __launch_bounds__(256)
void Forward_Model_27616639714074_kernel(const f32x4* __restrict__ in4,
                                         f32x4* __restrict__ out4,
                                         const float* __restrict__ w,
                                         unsigned int n4) {
    float c0  = fmaxf(rintf(w[0]), 0.001f);
    float c1  = fmaxf(rintf(w[1]), 0.001f);
    float l1s = 0.5f * fmaxf(rintf(w[2]), 0.001f);
    float l2s = 0.5f * fmaxf(rintf(w[3]), 0.001f);
    float sumsq = l1s * l1s + l2s * l2s;
    float rden  = 1.0f / (2.0f * l1s * l2s + 1e-6f);

    unsigned int i = blockIdx.x * 256u + threadIdx.x;
    if (i >= n4) return;
    f32x4 v = in4[i];
    float r0, r1, r2, r3;
    ik_solve(v.x, v.y, c0, c1, l1s, l2s, sumsq, rden, r0, r1);
    ik_solve(v.z, v.w, c0, c1, l1s, l2s, sumsq, rden, r2, r3);
    f32x4 r;
    r.x = r0; r.y = r1; r.z = r2; r.w = r3;
    __builtin_nontemporal_store(r, &out4[i]);
}

// tail: leftover (x,y) pairs past the float4 region (n always even)
__global__ __launch_bounds__(64)
void Forward_Model_27616639714074_tail(const float* __restrict__ in,
                                       float* __restrict__ out,
                                       const float* __restrict__ w,
                                       long long pair_start, long long n_pairs) {
    float c0  = fmaxf(rintf(w[0]), 0.001f);
    float c1  = fmaxf(rintf(w[1]), 0.001f);
    float l1s = 0.5f * fmaxf(rintf(w[2]), 0.001f);
    float l2s = 0.5f * fmaxf(rintf(w[3]), 0.001f);
    float sumsq = l1s * l1s + l2s * l2s;
    float rden  = 1.0f / (2.0f * l1s * l2s + 1e-6f);
    long long p = pair_start + blockIdx.x * 64 + threadIdx.x;
    if (p >= n_pairs) return;
    float t1, t2;
    ik_solve(in[p * 2 + 0], in[p * 2 + 1], c0, c1, l1s, l2s, sumsq, rden, t1, t2);
    out[p * 2 + 0] = t1;
    out[p * 2 + 1] = t2;
}

extern "C" void kernel_launch(void* const* d_in, const int* in_sizes, int n_in,
                              void* d_out, int out_size, void* d_ws, size_t ws_size,
                              hipStream_t stream) {
    const float* in = (const float*)d_in[0];
    const float* w  = (const float*)d_in[1];
    float* out = (float*)d_out;

    long long n = in_sizes[0];           // SIZE*2 floats per mult
    int n_mults = in_sizes[1] / 4;       // N_MULTS

    unsigned int n4 = (unsigned int)(n >> 2);          // float4 groups
    unsigned int grid = (n4 + 255u) / 256u;
    long long pair_start = ((long long)n4 << 2) >> 1;  // first pair past float4 region
    long long n_pairs = n >> 1;
    long long tail_pairs = n_pairs - pair_start;

    for (int ii = 0; ii < n_mults; ++ii) {
        const f32x4* in4 = reinterpret_cast<const f32x4*>(in);
        f32x4* out4 = reinterpret_cast<f32x4*>(out + (long long)ii * n);
        Forward_Model_27616639714074_kernel<<<grid, 256, 0, stream>>>(
            in4, out4, w + ii * 4, n4);
        if (tail_pairs > 0) {
            unsigned int tgrid = (unsigned int)((tail_pairs + 63) / 64);
            Forward_Model_27616639714074_tail<<<tgrid, 64, 0, stream>>>(
                in, out + (long long)ii * n, w + ii * 4, pair_start, n_pairs);
        }
    }
}